// Round 4
// baseline (7236.000 us; speedup 1.0000x reference)
//
#include <hip/hip_runtime.h>

typedef unsigned char u8;
typedef unsigned int u32;
typedef unsigned long long u64;

#define T_DIM 64
#define B_DIM 8
#define N_DIM 64
#define D_DIM 384
#define H_DIM 8
#define HD 48
#define M_ROWS 32768            // T*B*N = rows of every GEMM
#define CH 196608               // B*N*D = channels per LIF step (also B*T*D)
#define STATS_BLOCKS 256        // m-tiles (128 rows each)

// ---------------------------------------------------------------------------
// GEMM (NT) + fused BN-stats partials.  C[m,n] = sum_k X[m,k]*W[n,k].
// 512 threads = 8 waves per block; block tile 128x64; each WAVE owns a
// private 16x64 sub-tile and a PRIVATE double-buffered LDS stage (BK=8).
// NO __syncthreads in the main loop: waves self-pace on their own
// vmcnt/lgkmcnt, drifting freely to hide each other's latencies.
// LDS patterns are <=2-way (free).  Accumulation order k=0..383 sequential
// (bit-identical to prior passing rounds).
// ---------------------------------------------------------------------------
#define GBK 8
#define GKS (D_DIM / GBK)       // 48 K-steps

union ShU {
  struct { float As[8][2][GBK][16]; float Bs[8][2][GBK][64]; } mm;  // 8KB+32KB
  struct { double s[8][4][64]; double q[8][4][64]; } red;           // 32KB
};

__global__ __launch_bounds__(512, 8) void gemm_bn(const float* __restrict__ X,
                                                  const float* __restrict__ W,
                                                  float* __restrict__ C,
                                                  double* __restrict__ part) {
  __shared__ ShU sh;
  const int tid = threadIdx.x;
  const int w = tid >> 6;          // wave 0..7
  const int lane = tid & 63;
  const int bn = blockIdx.x * 64;  // 0..5 -> col base
  const int by = blockIdx.y;       // 0..255
  const int bm = by * 128 + w * 16;  // wave's 16-row base
  const int tx = lane & 15;        // cols 4tx..4tx+3
  const int tyw = lane >> 4;       // row group 0..3 within wave

  // staging assignments
  const int r2 = lane >> 1;        // 0..31
  const int kq4 = (lane & 1) * 4;  // k offset 0 or 4
  const float* xp = X + (size_t)(bm + r2) * D_DIM + kq4;          // lanes<32
  const float* wp0 = W + (size_t)(bn + r2) * D_DIM + kq4;         // rows 0..31
  const float* wp1 = wp0 + (size_t)32 * D_DIM;                    // rows 32..63

  float4 av, b0v, b1v;

#define STAGE(buf)                                                        \
  do {                                                                    \
    if (lane < 32) {                                                      \
      sh.mm.As[w][buf][kq4 + 0][r2] = av.x;                               \
      sh.mm.As[w][buf][kq4 + 1][r2] = av.y;                               \
      sh.mm.As[w][buf][kq4 + 2][r2] = av.z;                               \
      sh.mm.As[w][buf][kq4 + 3][r2] = av.w;                               \
    }                                                                     \
    sh.mm.Bs[w][buf][kq4 + 0][r2] = b0v.x;                                \
    sh.mm.Bs[w][buf][kq4 + 1][r2] = b0v.y;                                \
    sh.mm.Bs[w][buf][kq4 + 2][r2] = b0v.z;                                \
    sh.mm.Bs[w][buf][kq4 + 3][r2] = b0v.w;                                \
    sh.mm.Bs[w][buf][kq4 + 0][32 + r2] = b1v.x;                           \
    sh.mm.Bs[w][buf][kq4 + 1][32 + r2] = b1v.y;                           \
    sh.mm.Bs[w][buf][kq4 + 2][32 + r2] = b1v.z;                           \
    sh.mm.Bs[w][buf][kq4 + 3][32 + r2] = b1v.w;                           \
  } while (0)

  // prologue: K-chunk 0 -> buf 0
  if (lane < 32) av = *(const float4*)xp;
  b0v = *(const float4*)wp0;
  b1v = *(const float4*)wp1;
  STAGE(0);

  float acc[4][4] = {};
  int cur = 0;

  for (int ks = 0; ks < GKS; ++ks) {
    if (ks < GKS - 1) {
      const int k0 = (ks + 1) * GBK;
      if (lane < 32) av = *(const float4*)(xp + k0);
      b0v = *(const float4*)(wp0 + k0);
      b1v = *(const float4*)(wp1 + k0);
    }
#pragma unroll
    for (int k = 0; k < GBK; ++k) {
      float4 a4 = *(const float4*)&sh.mm.As[w][cur][k][tyw * 4];
      float4 b4 = *(const float4*)&sh.mm.Bs[w][cur][k][tx * 4];
      float aa[4] = {a4.x, a4.y, a4.z, a4.w};
      float bb[4] = {b4.x, b4.y, b4.z, b4.w};
#pragma unroll
      for (int i = 0; i < 4; ++i)
#pragma unroll
        for (int j = 0; j < 4; ++j)
          acc[i][j] = fmaf(aa[i], bb[j], acc[i][j]);
    }
    if (ks < GKS - 1) {
      STAGE(cur ^ 1);
      cur ^= 1;
    }
  }
#undef STAGE

  // C write: 4 rows x float4, coalesced within wave
#pragma unroll
  for (int i = 0; i < 4; ++i) {
    float4 o = make_float4(acc[i][0], acc[i][1], acc[i][2], acc[i][3]);
    *(float4*)&C[(size_t)(bm + tyw * 4 + i) * D_DIM + bn + tx * 4] = o;
  }

  // fused BN partial stats (deterministic fixed order, f64).
  __syncthreads();  // all waves done with mm before union reuse
#pragma unroll
  for (int j = 0; j < 4; ++j) {
    double s = 0.0, qd = 0.0;
#pragma unroll
    for (int i = 0; i < 4; ++i) {
      const double v = (double)acc[i][j];
      s += v;
      qd += v * v;
    }
    sh.red.s[w][tyw][tx * 4 + j] = s;
    sh.red.q[w][tyw][tx * 4 + j] = qd;
  }
  __syncthreads();
  if (tid < 64) {
    double S = 0.0, Q = 0.0;
#pragma unroll
    for (int ww = 0; ww < 8; ++ww)
#pragma unroll
      for (int t2 = 0; t2 < 4; ++t2) {
        S += sh.red.s[ww][t2][tid];
        Q += sh.red.q[ww][t2][tid];
      }
    const size_t pidx = ((size_t)by * D_DIM + bn + tid) * 2;
    part[pidx + 0] = S;
    part[pidx + 1] = Q;
  }
}

// ---------------------------------------------------------------------------
// BN stats finalize: reduce 256 tile-partials per channel (fixed order, f64).
// ---------------------------------------------------------------------------
__global__ void bn_stats_final(const double* __restrict__ part,
                               const float* __restrict__ gamma,
                               const float* __restrict__ beta,
                               float* __restrict__ ss) {
  const int c = blockIdx.x * 64 + threadIdx.x;
  double s = 0.0, q = 0.0;
  for (int b = 0; b < STATS_BLOCKS; ++b) {
    s += part[((size_t)b * D_DIM + c) * 2 + 0];
    q += part[((size_t)b * D_DIM + c) * 2 + 1];
  }
  const double n = (double)M_ROWS;
  const double mean = s / n;
  const double var = q / n - mean * mean;
  const double rstd = 1.0 / sqrt(var + 1e-5);
  const double sc = (double)gamma[c] * rstd;
  ss[c * 2 + 0] = (float)sc;
  ss[c * 2 + 1] = (float)((double)beta[c] - mean * sc);
}

// ---------------------------------------------------------------------------
// LIF scan over leading axis (64 steps, stride CH), chunk-8 load prefetch.
// MODE 0: BN affine then LIF, write u8 spikes (branch q/k/v).
// MODE 2: BN affine then LIF, overwrite Y with f32 spikes (proj_lif).
// ---------------------------------------------------------------------------
template <int MODE>
__global__ __launch_bounds__(256) void lif_kernel(float* Y,
                                                  const float* __restrict__ ss,
                                                  u8* __restrict__ spikes) {
  const int c = blockIdx.x * 256 + threadIdx.x;
  const int dd = c % D_DIM;
  const float scale = ss[dd * 2 + 0];
  const float shift = ss[dd * 2 + 1];
  float v = 0.0f;
  for (int t0 = 0; t0 < T_DIM; t0 += 8) {
    float xs[8];
#pragma unroll
    for (int u = 0; u < 8; ++u) xs[u] = Y[(size_t)(t0 + u) * CH + c];
#pragma unroll
    for (int u = 0; u < 8; ++u) {
      const float xv = xs[u] * scale + shift;
      const float hh = v + (xv - v) * 0.5f;
      const float sp = (hh >= 1.0f) ? 1.0f : 0.0f;
      v = (1.0f - sp) * hh;
      if (MODE == 0)
        spikes[(size_t)(t0 + u) * CH + c] = (u8)sp;
      else
        Y[(size_t)(t0 + u) * CH + c] = sp;
    }
  }
}

// ---------------------------------------------------------------------------
// Attention + fused attn_lif. Block = (x,b,h). Spikes binary -> 48-bit masks,
// S[i][j] = popcount(q_i & k_j)*mask(i,j); Z[i][d] = sum_j S[i][j]*V[j][d].
// Then LIF over i per d-channel, writing f32 spikes in (i,b,x,h,d) layout.
// ---------------------------------------------------------------------------
__global__ __launch_bounds__(256) void attn_kernel(const u8* __restrict__ qs,
                                                   const u8* __restrict__ ks,
                                                   const u8* __restrict__ vs,
                                                   float* __restrict__ z) {
  const int gid = blockIdx.x;
  const int h = gid & 7;
  const int b = (gid >> 3) & 7;
  const int x = gid >> 6;
  const int tid = threadIdx.x;

  __shared__ u64 qb[64];
  __shared__ u64 kb[64];
  __shared__ float sS[64][65];
  __shared__ u8 sV[64][48];
  __shared__ float zb[64][49];

  if (tid < 64) {
    const int i = tid;  // Q row: qh[x, b, i, h, :]
    const u32* p = (const u32*)(qs + ((size_t)((x * B_DIM + b) * N_DIM + i)) * D_DIM + h * HD);
    u64 bits = 0;
#pragma unroll
    for (int w = 0; w < 12; ++w) {
      u32 u = p[w];
      u32 nib = (u & 1u) | ((u >> 7) & 2u) | ((u >> 14) & 4u) | ((u >> 21) & 8u);
      bits |= (u64)nib << (w * 4);
    }
    qb[i] = bits;
  } else if (tid < 128) {
    const int j = tid - 64;  // K row: kh[j, b, x, h, :]
    const u32* p = (const u32*)(ks + ((size_t)((j * B_DIM + b) * N_DIM + x)) * D_DIM + h * HD);
    u64 bits = 0;
#pragma unroll
    for (int w = 0; w < 12; ++w) {
      u32 u = p[w];
      u32 nib = (u & 1u) | ((u >> 7) & 2u) | ((u >> 14) & 4u) | ((u >> 21) & 8u);
      bits |= (u64)nib << (w * 4);
    }
    kb[j] = bits;
  } else if (tid < 192) {
    const int j = tid - 128;  // V row: vh[j, b, x, h, :]
    const u32* p = (const u32*)(vs + ((size_t)((j * B_DIM + b) * N_DIM + x)) * D_DIM + h * HD);
    u32* dst = (u32*)&sV[j][0];
#pragma unroll
    for (int w = 0; w < 12; ++w) dst[w] = p[w];
  }
  __syncthreads();

  // S phase
  {
    const int i = tid >> 2;
    const u64 qi = qb[i];
#pragma unroll
    for (int r = 0; r < 16; ++r) {
      const int j = ((tid & 3) << 4) + r;
      const int cnt = __popcll(qi & kb[j]);
      int ad = i - j;
      if (ad < 0) ad = -ad;
      sS[i][j] = (float)cnt * (1.0f / (float)(1 + ad));
    }
  }
  __syncthreads();

  // Z phase -> LDS
  const float kScale = 0.05103103630798287f;  // 384^-0.5
#pragma unroll
  for (int r = 0; r < 12; ++r) {
    const int o = (r << 8) + tid;
    const int i = o / HD;
    const int d = o - i * HD;
    float acc = 0.0f;
#pragma unroll
    for (int j = 0; j < 64; ++j)
      acc = fmaf(sS[i][j], (float)sV[j][d], acc);
    zb[i][d] = acc * kScale;
  }
  __syncthreads();

  // fused attn_lif: scan over i per d-channel, write f32 spikes
  if (tid < HD) {
    const int d = tid;
    float v = 0.0f;
    for (int i = 0; i < 64; ++i) {
      const float hh = v + (zb[i][d] - v) * 0.5f;
      const float sp = (hh >= 1.0f) ? 1.0f : 0.0f;
      v = (1.0f - sp) * hh;
      z[((size_t)((i * B_DIM + b) * T_DIM + x)) * D_DIM + h * HD + d] = sp;
    }
  }
}

// ---------------------------------------------------------------------------
extern "C" void kernel_launch(void* const* d_in, const int* in_sizes, int n_in,
                              void* d_out, int out_size, void* d_ws, size_t ws_size,
                              hipStream_t stream) {
  const float* q  = (const float*)d_in[0];
  const float* kv = (const float*)d_in[1];
  const float* Wq = (const float*)d_in[2];
  const float* gq = (const float*)d_in[3];
  const float* bq = (const float*)d_in[4];
  const float* Wk = (const float*)d_in[5];
  const float* gk = (const float*)d_in[6];
  const float* bk = (const float*)d_in[7];
  const float* Wv = (const float*)d_in[8];
  const float* gv = (const float*)d_in[9];
  const float* bv = (const float*)d_in[10];
  const float* Wp = (const float*)d_in[11];
  const float* gp = (const float*)d_in[12];
  const float* bp = (const float*)d_in[13];
  float* out = (float*)d_out;
  char* ws = (char*)d_ws;

  // workspace layout (bytes)
  float* Ybuf  = (float*)(ws + 0);                // 50,331,648  (Y, then z-spikes)
  u8* qsb      = (u8*)(ws + 50331648ull);         // 12,582,912
  u8* ksb      = (u8*)(ws + 62914560ull);         // 12,582,912
  u8* vsb      = (u8*)(ws + 75497472ull);         // 12,582,912
  double* part = (double*)(ws + 88080384ull);     //  1,572,864
  float* ss    = (float*)(ws + 89653248ull);      //      3,072

  dim3 gg(D_DIM / 64, M_ROWS / 128);  // (6, 256)

  // --- q branch ---
  gemm_bn<<<gg, 512, 0, stream>>>(q, Wq, Ybuf, part);
  bn_stats_final<<<6, 64, 0, stream>>>(part, gq, bq, ss);
  lif_kernel<0><<<CH / 256, 256, 0, stream>>>(Ybuf, ss, qsb);

  // --- k branch ---
  gemm_bn<<<gg, 512, 0, stream>>>(kv, Wk, Ybuf, part);
  bn_stats_final<<<6, 64, 0, stream>>>(part, gk, bk, ss);
  lif_kernel<0><<<CH / 256, 256, 0, stream>>>(Ybuf, ss, ksb);

  // --- v branch ---
  gemm_bn<<<gg, 512, 0, stream>>>(kv, Wv, Ybuf, part);
  bn_stats_final<<<6, 64, 0, stream>>>(part, gv, bv, ss);
  lif_kernel<0><<<CH / 256, 256, 0, stream>>>(Ybuf, ss, vsb);

  // --- attention + fused attn_lif (writes f32 spikes into Ybuf) ---
  attn_kernel<<<T_DIM * B_DIM * H_DIM, 256, 0, stream>>>(qsb, ksb, vsb, Ybuf);

  // --- proj GEMM -> d_out (+ fused stats), then proj_lif in place ---
  gemm_bn<<<gg, 512, 0, stream>>>(Ybuf, Wp, out, part);
  bn_stats_final<<<6, 64, 0, stream>>>(part, gp, bp, ss);
  lif_kernel<2><<<CH / 256, 256, 0, stream>>>(out, ss, (u8*)nullptr);
}